// Round 14
// baseline (206.752 us; speedup 1.0000x reference)
//
#include <hip/hip_runtime.h>

typedef unsigned short u16;
typedef unsigned int u32;
typedef _Float16 f16;
typedef __attribute__((ext_vector_type(4))) _Float16 f16x4;
typedef __attribute__((ext_vector_type(8))) _Float16 f16x8;
typedef __attribute__((ext_vector_type(4))) float f32x4;
typedef __fp16 hh2 __attribute__((ext_vector_type(2)));

#define BCAP 8192          // per-bucket pair capacity (mean 4096, sd 64)
#define BSH  8             // 256 nodes per bucket

__device__ __forceinline__ u32 pkrtz(float a, float b) {
  hh2 r = __builtin_amdgcn_cvt_pkrtz(a, b);
  union { hh2 h; u32 u; } c; c.h = r; return c.u;
}
__device__ __forceinline__ f16x4 mk4(u32 lo, u32 hi) {
  union { u32 u[2]; f16x4 h; } c; c.u[0] = lo; c.u[1] = hi; return c.h;
}
__device__ __forceinline__ f16x8 mk8(u32 a, u32 b, u32 c_, u32 d) {
  union { u32 u[4]; f16x8 h; } c; c.u[0] = a; c.u[1] = b; c.u[2] = c_; c.u[3] = d; return c.h;
}
__device__ __forceinline__ float fexp2(float x) {
  float r; asm("v_exp_f32 %0, %1" : "=v"(r) : "v"(x)); return r;
}

// ---------------- tiny zero kernel ----------------
__global__ void __launch_bounds__(256) k_zero(int* __restrict__ p, int n) {
  int i = threadIdx.x + blockIdx.x * 256;
  if (i < n) p[i] = 0;
}

// ---------------- front1: weight-prep blocks + bucketA blocks (independent) ----------------
__global__ void __launch_bounds__(256) k_front1(
    const float* __restrict__ Wl1, const float* __restrict__ bl1,
    const float* __restrict__ Wr1, const float* __restrict__ br1,
    const float* __restrict__ W1,  const float* __restrict__ b1,
    const float* __restrict__ Wl2, const float* __restrict__ bl2,
    const float* __restrict__ Wr2, const float* __restrict__ br2,
    const float* __restrict__ W2,  const float* __restrict__ b2,
    f16* __restrict__ Wf1, f16* __restrict__ Wf2,
    float* __restrict__ bias1, float* __restrict__ bias2,
    const int* __restrict__ ei, int* __restrict__ fillA, u32* __restrict__ pairs,
    int E, int NB, int GP)
{
  __shared__ int sm[1024];
  int b = blockIdx.x;
  int t = threadIdx.x;
  if (b < GP) {
    int g = b * 256 + t;
    const int NP1 = 12 * 4 * 64 * 8;   // 24576
    const int NP2 = 12 * 2 * 64 * 8;   // 12288
    if (g < NP1) {
      int j = g & 7, l = (g >> 3) & 63, s = (g >> 9) & 3, tt = g >> 11;
      int k = s * 32 + ((l >> 4) << 3) + j;
      int c = tt * 16 + (l & 15);
      const float* W = (c < 64) ? Wl1 : (c < 128 ? Wr1 : W1);
      Wf1[g] = (f16)W[k * 64 + (c & 63)];
    } else if (g < NP1 + NP2) {
      int g2 = g - NP1;
      int j = g2 & 7, l = (g2 >> 3) & 63, s = (g2 >> 9) & 1, tt = g2 >> 10;
      int k = s * 32 + ((l >> 4) << 3) + j;
      int c = tt * 16 + (l & 15);
      const float* W = (c < 64) ? Wl2 : (c < 128 ? Wr2 : W2);
      Wf2[g2] = (f16)W[k * 64 + (c & 63)];
    } else if (g < NP1 + NP2 + 192) {
      int c = g - NP1 - NP2;
      bias1[c] = (c < 64) ? bl1[c] : (c < 128 ? br1[c - 64] : b1[c - 128]);
    } else if (g < NP1 + NP2 + 384) {
      int c = g - NP1 - NP2 - 192;
      bias2[c] = (c < 64) ? bl2[c] : (c < 128 ? br2[c - 64] : b2[c - 128]);
    }
  } else {
    int* lhist = sm;
    int* lbase = sm + 512;
    int c0 = (b - GP) * 8192;
    int n = E - c0; if (n > 8192) n = 8192;
    for (int i = t; i < NB; i += 256) lhist[i] = 0;
    __syncthreads();
    for (int i = t; i < n; i += 256)
      atomicAdd(&lhist[ei[E + c0 + i] >> BSH], 1);
    __syncthreads();
    for (int i = t; i < NB; i += 256) {
      int h = lhist[i];
      lbase[i] = h ? atomicAdd(&fillA[i], h) : 0;
      lhist[i] = 0;
    }
    __syncthreads();
    for (int i = t; i < n; i += 256) {
      int s = ei[c0 + i], d = ei[E + c0 + i];
      int bk = d >> BSH;
      int pos = lbase[bk] + atomicAdd(&lhist[bk], 1);
      if (pos < BCAP) pairs[(size_t)bk * BCAP + pos] = ((u32)s << 8) | (u32)(d & 255);
    }
  }
}

// ---------------- front2: gemm1 blocks + bucketB blocks (independent) ----------------
// bucketB packs srcs as (dst&15)<<28 | src  (src < 2^24) for the tile-based conv.
__global__ void __launch_bounds__(256) k_front2(
    const float* __restrict__ X, const f16* __restrict__ Wfrag, const float* __restrict__ bias,
    f16* __restrict__ O0, f16* __restrict__ O1, f16* __restrict__ O2, int N, int GG,
    const u32* __restrict__ pairs, const int* __restrict__ fillA,
    u32* __restrict__ srcs, int* __restrict__ offs, int NB, int E)
{
  __shared__ __align__(16) char smraw[49152];
  int b = blockIdx.x;
  int t = threadIdx.x;
  if (b < GG) {
    constexpr int KS = 4, K = 128;
    f16* wl = (f16*)smraw;
    {
      const int4* src = (const int4*)Wfrag;
      int4* dst = (int4*)wl;
      const int n16 = 12 * KS * 64;
      for (int i = t; i < n16; i += 256) dst[i] = src[i];
    }
    __syncthreads();
    int lane = t & 63, w = t >> 6;
    int g8 = ((lane >> 4) << 3);
    int r16 = b * 64 + w * 16;
    int rowA = r16 + (lane & 15);
    int rowAc = rowA < N ? rowA : N - 1;
    int colc = lane & 15;
    f32x4 acc[12];
#pragma unroll
    for (int tt = 0; tt < 12; ++tt) {
      float bb_ = bias[tt * 16 + colc];
      f32x4 tmp = {bb_, bb_, bb_, bb_};
      acc[tt] = tmp;
    }
#pragma unroll
    for (int s = 0; s < KS; ++s) {
      const float* xp = X + (size_t)rowAc * K + s * 32 + g8;
      float4 x0 = *(const float4*)xp;
      float4 x1 = *(const float4*)(xp + 4);
      f16x8 a = mk8(pkrtz(x0.x, x0.y), pkrtz(x0.z, x0.w),
                    pkrtz(x1.x, x1.y), pkrtz(x1.z, x1.w));
#pragma unroll
      for (int tt = 0; tt < 12; ++tt) {
        f16x8 bb_ = *(const f16x8*)&wl[((tt * KS + s) * 64 + lane) * 8];
        acc[tt] = __builtin_amdgcn_mfma_f32_16x16x32_f16(a, bb_, acc[tt], 0, 0, 0);
      }
    }
    int rowD0 = r16 + ((lane >> 4) << 2);
#pragma unroll
    for (int tt = 0; tt < 12; ++tt) {
      f16* O = (tt < 4) ? O0 : (tt < 8 ? O1 : O2);
      int c = (tt & 3) * 16 + colc;
#pragma unroll
      for (int q = 0; q < 4; ++q) {
        int r = rowD0 + q;
        if (r < N) O[(size_t)r * 64 + c] = (f16)acc[tt][q];
      }
    }
  } else {
    int* cnt   = (int*)smraw;
    int* lfill = cnt + 256;
    int* ps    = lfill + 256;
    int* lsrc  = ps + 256;
    int bk = b - GG;
    int a0 = (2 * t < NB) ? fillA[2 * t] : 0;
    int a1 = (2 * t + 1 < NB) ? fillA[2 * t + 1] : 0;
    ps[t] = a0 + a1;
    __syncthreads();
    for (int d = 1; d < 256; d <<= 1) {
      int x = (t >= d) ? ps[t - d] : 0;
      __syncthreads();
      ps[t] += x;
      __syncthreads();
    }
    int pi = bk >> 1;
    int base = (pi ? ps[pi - 1] : 0) + ((bk & 1) ? fillA[bk & ~1] : 0);
    int m = fillA[bk];
    int n0 = bk << BSH;
    if (bk == 0 && t == 0) offs[N] = E;
    const u32* P = pairs + (size_t)bk * BCAP;
    cnt[t] = 0;
    __syncthreads();
    for (int i = t; i < m; i += 256)
      atomicAdd(&cnt[P[i] & 255], 1);
    __syncthreads();
    int v = cnt[t];
    lfill[t] = v;
    __syncthreads();
    for (int d = 1; d < 256; d <<= 1) {
      int a = (t >= d) ? lfill[t - d] : 0;
      __syncthreads();
      lfill[t] += a;
      __syncthreads();
    }
    int excl = lfill[t] - v;
    if (n0 + t < N) offs[n0 + t] = base + excl;
    __syncthreads();
    lfill[t] = excl;
    __syncthreads();
    for (int i = t; i < m; i += 256) {
      u32 p = P[i];
      int pos = atomicAdd(&lfill[p & 255], 1);
      lsrc[pos] = (int)(((p & 15u) << 28) | (p >> 8));   // (dst&15)<<28 | src
    }
    __syncthreads();
    for (int i = t; i < m; i += 256) srcs[base + i] = (u32)lsrc[i];
  }
}

// ---------------- standalone gemm (layer 2): [N,64] @ [64,192], f16 in/out ----------------
__global__ void __launch_bounds__(256) k_gemm2(const f16* __restrict__ Xv,
    const f16* __restrict__ Wfrag, const float* __restrict__ bias,
    f16* __restrict__ O0, f16* __restrict__ O1, f16* __restrict__ O2, int N)
{
  constexpr int KS = 2, K = 64;
  __shared__ f16 wl[12 * KS * 64 * 8];
  const int tid = threadIdx.x;
  {
    const int4* src = (const int4*)Wfrag;
    int4* dst = (int4*)wl;
    const int n16 = 12 * KS * 64;
    for (int i = tid; i < n16; i += 256) dst[i] = src[i];
  }
  __syncthreads();
  int lane = tid & 63, w = tid >> 6;
  int g8 = ((lane >> 4) << 3);
  int r16 = blockIdx.x * 64 + w * 16;
  int rowA = r16 + (lane & 15);
  int rowAc = rowA < N ? rowA : N - 1;
  int colc = lane & 15;
  f32x4 acc[12];
#pragma unroll
  for (int t = 0; t < 12; ++t) {
    float b = bias[t * 16 + colc];
    f32x4 tmp = {b, b, b, b};
    acc[t] = tmp;
  }
#pragma unroll
  for (int s = 0; s < KS; ++s) {
    f16x8 a = *(const f16x8*)(Xv + (size_t)rowAc * K + s * 32 + g8);
#pragma unroll
    for (int t = 0; t < 12; ++t) {
      f16x8 b = *(const f16x8*)&wl[((t * KS + s) * 64 + lane) * 8];
      acc[t] = __builtin_amdgcn_mfma_f32_16x16x32_f16(a, b, acc[t], 0, 0, 0);
    }
  }
  int rowD0 = r16 + ((lane >> 4) << 2);
#pragma unroll
  for (int t = 0; t < 12; ++t) {
    f16* O = (t < 4) ? O0 : (t < 8 ? O1 : O2);
    int c = (t & 3) * 16 + colc;
#pragma unroll
    for (int q = 0; q < 4; ++q) {
      int r = rowD0 + q;
      if (r < N) O[(size_t)r * 64 + c] = (f16)acc[t][q];
    }
  }
}

// ---------------- tile-based segment-matmul GATv2 conv, 2-deep 3-buffer pipeline -------------
// 16 consecutive (16-aligned) nodes per wave = one contiguous CSR edge range.
// Rotation: compute buf[k%3], prefetch k+3 into buf[k%3] -> each gather gets ~2 batch-bodies
// of latency cover. Buffer = XL(2xf16x8) + XR(2xf16x8) + packed dst-nibbles (1 u32).
// Exact tail (no masked-batch inflation - R11 lesson).
__global__ void __launch_bounds__(256) k_conv(const int* __restrict__ offs, const u32* __restrict__ srcs,
    const f16* __restrict__ XL, const f16* __restrict__ XR,
    const float* __restrict__ ATT, const float* __restrict__ BC,
    const f16* __restrict__ RES, f16* __restrict__ OH, float* __restrict__ OF,
    int N, int ntiles, int nwaves)
{
  int lane = threadIdx.x & 63, w = threadIdx.x >> 6;
  int g = lane >> 4, c16 = lane & 15;
  int wid = blockIdx.x * 4 + w;

  const float LOG2E = 1.4426950408889634f;
  f16x8 attf0, attf1, Ia, Ib;
#pragma unroll
  for (int j = 0; j < 8; ++j) {
    attf0[j] = (f16)(ATT[g * 8 + j] * LOG2E);
    attf1[j] = (f16)(ATT[32 + g * 8 + j] * LOG2E);
    Ia[j] = (f16)((g * 8 + j == c16) ? 1.f : 0.f);
    Ib[j] = (f16)((g * 8 + j == c16 + 16) ? 1.f : 0.f);
  }
  float bc4[4];
#pragma unroll
  for (int b = 0; b < 4; ++b) bc4[b] = BC[b * 16 + c16];
  const f16 one = (f16)1.f;
  const f16x4 ones = {one, one, one, one};

  for (int tile = wid; tile < ntiles; tile += nwaves) {
    int n0 = tile << 4;
    int nhi = n0 + 16; if (nhi > N) nhi = N;
    int e0 = __builtin_amdgcn_readfirstlane(offs[n0]);
    int e1 = __builtin_amdgcn_readfirstlane(offs[nhi]);
    int cnt = e1 - e0;

    f32x4 agg0 = {0.f, 0.f, 0.f, 0.f}, agg1 = agg0, agg2 = agg0, agg3 = agg0;
    f32x4 den = agg0;

    if (cnt > 0) {
      int nb = (cnt + 15) >> 4;
      u32 my = 0;
      f16x8 Ax0, Ax1, Ar0, Ar1; u32 Adp = 0;
      f16x8 Bx0, Bx1, Br0, Br1; u32 Bdp = 0;
      f16x8 Cx0, Cx1, Cr0, Cr1; u32 Cdp = 0;

#define PREFETCH(Px0, Px1, Pr0, Pr1, Pdp, k)                                    \
      if ((k) < nb) {                                                           \
        if (((k) & 3) == 0) {                                                   \
          int ein = e0 + ((k) << 4) + lane;                                     \
          my = srcs[ein < e1 ? ein : e1 - 1];                                   \
        }                                                                       \
        int nw_ = (k) & 3;                                                      \
        u32 vA = __shfl((int)my, (nw_ << 4) + c16);                             \
        const f16* rp = XL + (size_t)(vA & 0x0FFFFFFFu) * 64;                   \
        Px0 = *(const f16x8*)(rp + g * 8);                                      \
        Px1 = *(const f16x8*)(rp + 32 + g * 8);                                 \
        const f16* xp = XR + (size_t)(n0 + (int)(vA >> 28)) * 64;               \
        Pr0 = *(const f16x8*)(xp + g * 8);                                      \
        Pr1 = *(const f16x8*)(xp + 32 + g * 8);                                 \
        u32 w0 = __shfl((int)my, (nw_ << 4) + g * 4 + 0);                       \
        u32 w1 = __shfl((int)my, (nw_ << 4) + g * 4 + 1);                       \
        u32 w2 = __shfl((int)my, (nw_ << 4) + g * 4 + 2);                       \
        u32 w3 = __shfl((int)my, (nw_ << 4) + g * 4 + 3);                       \
        Pdp = (w0 >> 28) | ((w1 >> 28) << 4) | ((w2 >> 28) << 8) | ((w3 >> 28) << 12); \
      }

#define COMPUTE(Px0, Px1, Pr0, Pr1, Pdp, fb)                                    \
      {                                                                         \
        f16x8 t0 = Px0 + Pr0, t1 = Px1 + Pr1;                                   \
        t0 = __builtin_elementwise_max(t0, t0 * (f16)0.2f);                     \
        t1 = __builtin_elementwise_max(t1, t1 * (f16)0.2f);                     \
        f32x4 dot = {0.f, 0.f, 0.f, 0.f};                                       \
        dot = __builtin_amdgcn_mfma_f32_16x16x32_f16(t0, attf0, dot, 0, 0, 0);  \
        dot = __builtin_amdgcn_mfma_f32_16x16x32_f16(t1, attf1, dot, 0, 0, 0);  \
        f32x4 d0 = {0.f, 0.f, 0.f, 0.f}, d1 = d0, d2 = d0, d3 = d0;             \
        d0 = __builtin_amdgcn_mfma_f32_16x16x32_f16(Px0, Ia, d0, 0, 0, 0);      \
        d1 = __builtin_amdgcn_mfma_f32_16x16x32_f16(Px0, Ib, d1, 0, 0, 0);      \
        d2 = __builtin_amdgcn_mfma_f32_16x16x32_f16(Px1, Ia, d2, 0, 0, 0);      \
        d3 = __builtin_amdgcn_mfma_f32_16x16x32_f16(Px1, Ib, d3, 0, 0, 0);      \
        int eb = ((fb) << 4) + g * 4;                                           \
        float q0 = ((int)((Pdp >>  0) & 15u) == c16 && eb + 0 < cnt) ? fexp2(dot[0]) : 0.f; \
        float q1 = ((int)((Pdp >>  4) & 15u) == c16 && eb + 1 < cnt) ? fexp2(dot[1]) : 0.f; \
        float q2 = ((int)((Pdp >>  8) & 15u) == c16 && eb + 2 < cnt) ? fexp2(dot[2]) : 0.f; \
        float q3 = ((int)((Pdp >> 12) & 15u) == c16 && eb + 3 < cnt) ? fexp2(dot[3]) : 0.f; \
        f16x4 pa  = mk4(pkrtz(q0, q1), pkrtz(q2, q3));                          \
        f16x4 bv0 = mk4(pkrtz(d0[0], d0[1]), pkrtz(d0[2], d0[3]));              \
        f16x4 bv1 = mk4(pkrtz(d1[0], d1[1]), pkrtz(d1[2], d1[3]));              \
        f16x4 bv2 = mk4(pkrtz(d2[0], d2[1]), pkrtz(d2[2], d2[3]));              \
        f16x4 bv3 = mk4(pkrtz(d3[0], d3[1]), pkrtz(d3[2], d3[3]));              \
        agg0 = __builtin_amdgcn_mfma_f32_16x16x16f16(pa, bv0, agg0, 0, 0, 0);   \
        agg1 = __builtin_amdgcn_mfma_f32_16x16x16f16(pa, bv1, agg1, 0, 0, 0);   \
        agg2 = __builtin_amdgcn_mfma_f32_16x16x16f16(pa, bv2, agg2, 0, 0, 0);   \
        agg3 = __builtin_amdgcn_mfma_f32_16x16x16f16(pa, bv3, agg3, 0, 0, 0);   \
        den  = __builtin_amdgcn_mfma_f32_16x16x16f16(pa, ones, den, 0, 0, 0);   \
      }

      PREFETCH(Ax0, Ax1, Ar0, Ar1, Adp, 0)
      PREFETCH(Bx0, Bx1, Br0, Br1, Bdp, 1)
      PREFETCH(Cx0, Cx1, Cr0, Cr1, Cdp, 2)

      int fb = 0;
      for (; fb + 3 <= nb; fb += 3) {
        COMPUTE(Ax0, Ax1, Ar0, Ar1, Adp, fb)
        PREFETCH(Ax0, Ax1, Ar0, Ar1, Adp, fb + 3)
        COMPUTE(Bx0, Bx1, Br0, Br1, Bdp, fb + 1)
        PREFETCH(Bx0, Bx1, Br0, Br1, Bdp, fb + 4)
        COMPUTE(Cx0, Cx1, Cr0, Cr1, Cdp, fb + 2)
        PREFETCH(Cx0, Cx1, Cr0, Cr1, Cdp, fb + 5)
      }
      int rem = nb - fb;
      if (rem > 0) COMPUTE(Ax0, Ax1, Ar0, Ar1, Adp, fb)
      if (rem > 1) COMPUTE(Bx0, Bx1, Br0, Br1, Bdp, fb + 1)
#undef PREFETCH
#undef COMPUTE
    }

    // RES tile via vector load + identity MFMAs: r_b[q] = RES[n0+g*4+q][b*16+c16]
    int rowx = n0 + c16; if (rowx >= N) rowx = N - 1;
    const f16* rsp = RES + (size_t)rowx * 64;
    f16x8 rr0 = *(const f16x8*)(rsp + g * 8);
    f16x8 rr1 = *(const f16x8*)(rsp + 32 + g * 8);
    f32x4 r0 = {0.f, 0.f, 0.f, 0.f}, r1 = r0, r2 = r0, r3 = r0;
    r0 = __builtin_amdgcn_mfma_f32_16x16x32_f16(rr0, Ia, r0, 0, 0, 0);
    r1 = __builtin_amdgcn_mfma_f32_16x16x32_f16(rr0, Ib, r1, 0, 0, 0);
    r2 = __builtin_amdgcn_mfma_f32_16x16x32_f16(rr1, Ia, r2, 0, 0, 0);
    r3 = __builtin_amdgcn_mfma_f32_16x16x32_f16(rr1, Ib, r3, 0, 0, 0);

    // lane(g,c16) holds node n0+g*4+q, chan b*16+c16
#pragma unroll
    for (int q = 0; q < 4; ++q) {
      int node = n0 + g * 4 + q;
      if (node >= N) break;
      float dv = den[q];
      float rden = dv > 0.f ? 1.f / dv : 0.f;
#pragma unroll
      for (int b = 0; b < 4; ++b) {
        float av = (b == 0) ? agg0[q] : (b == 1) ? agg1[q] : (b == 2) ? agg2[q] : agg3[q];
        float rv = (b == 0) ? r0[q]   : (b == 1) ? r1[q]   : (b == 2) ? r2[q]   : r3[q];
        float o = av * rden + bc4[b] + rv;
        if (OH) { o = fmaxf(o, 0.f); OH[(size_t)node * 64 + b * 16 + c16] = (f16)o; }
        else    { OF[(size_t)node * 64 + b * 16 + c16] = o; }
      }
    }
  }
}

extern "C" void kernel_launch(void* const* d_in, const int* in_sizes, int n_in,
                              void* d_out, int out_size, void* d_ws, size_t ws_size,
                              hipStream_t stream) {
  const float* x   = (const float*)d_in[0];
  const int*   ei  = (const int*)d_in[1];
  const float* Wl1 = (const float*)d_in[3];
  const float* bl1 = (const float*)d_in[4];
  const float* Wr1 = (const float*)d_in[5];
  const float* br1 = (const float*)d_in[6];
  const float* att1= (const float*)d_in[7];
  const float* bc1 = (const float*)d_in[8];
  const float* W1  = (const float*)d_in[9];
  const float* b1  = (const float*)d_in[10];
  const float* Wl2 = (const float*)d_in[11];
  const float* bl2 = (const float*)d_in[12];
  const float* Wr2 = (const float*)d_in[13];
  const float* br2 = (const float*)d_in[14];
  const float* att2= (const float*)d_in[15];
  const float* bc2 = (const float*)d_in[16];
  const float* W2  = (const float*)d_in[17];
  const float* b2  = (const float*)d_in[18];

  const int N = in_sizes[0] / 128;
  const int E = in_sizes[1] / 2;
  const int NB = (N + 255) >> BSH;

  char* base = (char*)d_ws;
  size_t off = 0;
  auto take = [&](size_t bytes) -> void* {
    void* p = base + off;
    off = (off + bytes + 255) & ~(size_t)255;
    return p;
  };
  int* fillA = (int*)take((size_t)NB * 4);
  int* offs  = (int*)take((size_t)(N + 1) * 4);
  u32* pairs = (u32*)take((size_t)NB * BCAP * 4);
  u32* srcs  = (u32*)take((size_t)E * 4);
  f16* Wf1   = (f16*)take(12 * 4 * 64 * 8 * 2);
  f16* Wf2   = (f16*)take(12 * 2 * 64 * 8 * 2);
  float* bias1 = (float*)take(192 * 4);
  float* bias2 = (float*)take(192 * 4);
  f16* xl  = (f16*)take((size_t)N * 64 * 2);
  f16* xr  = (f16*)take((size_t)N * 64 * 2);
  f16* rs  = (f16*)take((size_t)N * 64 * 2);
  f16* h   = (f16*)take((size_t)N * 64 * 2);

  k_zero<<<(NB + 255) / 256, 256, 0, stream>>>(fillA, NB);

  const int prepN = 12 * 4 * 64 * 8 + 12 * 2 * 64 * 8 + 384;
  const int GP = (prepN + 255) / 256;
  const int GA = (E + 8191) / 8192;
  k_front1<<<GP + GA, 256, 0, stream>>>(Wl1, bl1, Wr1, br1, W1, b1,
                                        Wl2, bl2, Wr2, br2, W2, b2,
                                        Wf1, Wf2, bias1, bias2,
                                        ei, fillA, pairs, E, NB, GP);

  const int GG = (N + 63) / 64;
  k_front2<<<GG + NB, 256, 0, stream>>>(x, Wf1, bias1, xl, xr, rs, N, GG,
                                        pairs, fillA, srcs, offs, NB, E);

  const int ntiles = (N + 15) / 16;
  const int CB = 1563, CW = CB * 4;   // ~1 tile per wave
  k_conv<<<CB, 256, 0, stream>>>(offs, srcs, xl, xr, att1, bc1, rs, h, nullptr, N, ntiles, CW);
  k_gemm2<<<GG, 256, 0, stream>>>(h, Wf2, bias2, xl, xr, rs, N);
  k_conv<<<CB, 256, 0, stream>>>(offs, srcs, xl, xr, att2, bc2, rs, nullptr, (float*)d_out, N, ntiles, CW);
}

// Round 15
// 194.267 us; speedup vs baseline: 1.0643x; 1.0643x over previous
//
#include <hip/hip_runtime.h>

typedef unsigned short u16;
typedef unsigned int u32;
typedef _Float16 f16;
typedef __attribute__((ext_vector_type(4))) _Float16 f16x4;
typedef __attribute__((ext_vector_type(8))) _Float16 f16x8;
typedef __attribute__((ext_vector_type(4))) float f32x4;
typedef __fp16 hh2 __attribute__((ext_vector_type(2)));

#define BCAP 8192          // per-bucket pair capacity (mean 4096, sd 64)
#define BSH  8             // 256 nodes per bucket

__device__ __forceinline__ u32 pkrtz(float a, float b) {
  hh2 r = __builtin_amdgcn_cvt_pkrtz(a, b);
  union { hh2 h; u32 u; } c; c.h = r; return c.u;
}
__device__ __forceinline__ f16x4 mk4(u32 lo, u32 hi) {
  union { u32 u[2]; f16x4 h; } c; c.u[0] = lo; c.u[1] = hi; return c.h;
}
__device__ __forceinline__ f16x8 mk8(u32 a, u32 b, u32 c_, u32 d) {
  union { u32 u[4]; f16x8 h; } c; c.u[0] = a; c.u[1] = b; c.u[2] = c_; c.u[3] = d; return c.h;
}
__device__ __forceinline__ float fexp2(float x) {
  float r; asm("v_exp_f32 %0, %1" : "=v"(r) : "v"(x)); return r;
}

// ---------------- tiny zero kernel ----------------
__global__ void __launch_bounds__(256) k_zero(int* __restrict__ p, int n) {
  int i = threadIdx.x + blockIdx.x * 256;
  if (i < n) p[i] = 0;
}

// ---------------- front1: weight-prep blocks + bucketA blocks (independent) ----------------
__global__ void __launch_bounds__(256) k_front1(
    const float* __restrict__ Wl1, const float* __restrict__ bl1,
    const float* __restrict__ Wr1, const float* __restrict__ br1,
    const float* __restrict__ W1,  const float* __restrict__ b1,
    const float* __restrict__ Wl2, const float* __restrict__ bl2,
    const float* __restrict__ Wr2, const float* __restrict__ br2,
    const float* __restrict__ W2,  const float* __restrict__ b2,
    f16* __restrict__ Wf1, f16* __restrict__ Wf2,
    float* __restrict__ bias1, float* __restrict__ bias2,
    const int* __restrict__ ei, int* __restrict__ fillA, u32* __restrict__ pairs,
    int E, int NB, int GP)
{
  __shared__ int sm[1024];
  int b = blockIdx.x;
  int t = threadIdx.x;
  if (b < GP) {
    int g = b * 256 + t;
    const int NP1 = 12 * 4 * 64 * 8;   // 24576
    const int NP2 = 12 * 2 * 64 * 8;   // 12288
    if (g < NP1) {
      int j = g & 7, l = (g >> 3) & 63, s = (g >> 9) & 3, tt = g >> 11;
      int k = s * 32 + ((l >> 4) << 3) + j;
      int c = tt * 16 + (l & 15);
      const float* W = (c < 64) ? Wl1 : (c < 128 ? Wr1 : W1);
      Wf1[g] = (f16)W[k * 64 + (c & 63)];
    } else if (g < NP1 + NP2) {
      int g2 = g - NP1;
      int j = g2 & 7, l = (g2 >> 3) & 63, s = (g2 >> 9) & 1, tt = g2 >> 10;
      int k = s * 32 + ((l >> 4) << 3) + j;
      int c = tt * 16 + (l & 15);
      const float* W = (c < 64) ? Wl2 : (c < 128 ? Wr2 : W2);
      Wf2[g2] = (f16)W[k * 64 + (c & 63)];
    } else if (g < NP1 + NP2 + 192) {
      int c = g - NP1 - NP2;
      bias1[c] = (c < 64) ? bl1[c] : (c < 128 ? br1[c - 64] : b1[c - 128]);
    } else if (g < NP1 + NP2 + 384) {
      int c = g - NP1 - NP2 - 192;
      bias2[c] = (c < 64) ? bl2[c] : (c < 128 ? br2[c - 64] : b2[c - 128]);
    }
  } else {
    int* lhist = sm;
    int* lbase = sm + 512;
    int c0 = (b - GP) * 8192;
    int n = E - c0; if (n > 8192) n = 8192;
    for (int i = t; i < NB; i += 256) lhist[i] = 0;
    __syncthreads();
    for (int i = t; i < n; i += 256)
      atomicAdd(&lhist[ei[E + c0 + i] >> BSH], 1);
    __syncthreads();
    for (int i = t; i < NB; i += 256) {
      int h = lhist[i];
      lbase[i] = h ? atomicAdd(&fillA[i], h) : 0;
      lhist[i] = 0;
    }
    __syncthreads();
    for (int i = t; i < n; i += 256) {
      int s = ei[c0 + i], d = ei[E + c0 + i];
      int bk = d >> BSH;
      int pos = lbase[bk] + atomicAdd(&lhist[bk], 1);
      if (pos < BCAP) pairs[(size_t)bk * BCAP + pos] = ((u32)s << 8) | (u32)(d & 255);
    }
  }
}

// ---------------- front2: gemm1 blocks + bucketB blocks (independent) ----------------
// bucketB packs srcs as (dst&15)<<28 | src  (src < 2^24) for the tile-based conv.
__global__ void __launch_bounds__(256) k_front2(
    const float* __restrict__ X, const f16* __restrict__ Wfrag, const float* __restrict__ bias,
    f16* __restrict__ O0, f16* __restrict__ O1, f16* __restrict__ O2, int N, int GG,
    const u32* __restrict__ pairs, const int* __restrict__ fillA,
    u32* __restrict__ srcs, int* __restrict__ offs, int NB, int E)
{
  __shared__ __align__(16) char smraw[49152];
  int b = blockIdx.x;
  int t = threadIdx.x;
  if (b < GG) {
    constexpr int KS = 4, K = 128;
    f16* wl = (f16*)smraw;
    {
      const int4* src = (const int4*)Wfrag;
      int4* dst = (int4*)wl;
      const int n16 = 12 * KS * 64;
      for (int i = t; i < n16; i += 256) dst[i] = src[i];
    }
    __syncthreads();
    int lane = t & 63, w = t >> 6;
    int g8 = ((lane >> 4) << 3);
    int r16 = b * 64 + w * 16;
    int rowA = r16 + (lane & 15);
    int rowAc = rowA < N ? rowA : N - 1;
    int colc = lane & 15;
    f32x4 acc[12];
#pragma unroll
    for (int tt = 0; tt < 12; ++tt) {
      float bb_ = bias[tt * 16 + colc];
      f32x4 tmp = {bb_, bb_, bb_, bb_};
      acc[tt] = tmp;
    }
#pragma unroll
    for (int s = 0; s < KS; ++s) {
      const float* xp = X + (size_t)rowAc * K + s * 32 + g8;
      float4 x0 = *(const float4*)xp;
      float4 x1 = *(const float4*)(xp + 4);
      f16x8 a = mk8(pkrtz(x0.x, x0.y), pkrtz(x0.z, x0.w),
                    pkrtz(x1.x, x1.y), pkrtz(x1.z, x1.w));
#pragma unroll
      for (int tt = 0; tt < 12; ++tt) {
        f16x8 bb_ = *(const f16x8*)&wl[((tt * KS + s) * 64 + lane) * 8];
        acc[tt] = __builtin_amdgcn_mfma_f32_16x16x32_f16(a, bb_, acc[tt], 0, 0, 0);
      }
    }
    int rowD0 = r16 + ((lane >> 4) << 2);
#pragma unroll
    for (int tt = 0; tt < 12; ++tt) {
      f16* O = (tt < 4) ? O0 : (tt < 8 ? O1 : O2);
      int c = (tt & 3) * 16 + colc;
#pragma unroll
      for (int q = 0; q < 4; ++q) {
        int r = rowD0 + q;
        if (r < N) O[(size_t)r * 64 + c] = (f16)acc[tt][q];
      }
    }
  } else {
    int* cnt   = (int*)smraw;
    int* lfill = cnt + 256;
    int* ps    = lfill + 256;
    int* lsrc  = ps + 256;
    int bk = b - GG;
    int a0 = (2 * t < NB) ? fillA[2 * t] : 0;
    int a1 = (2 * t + 1 < NB) ? fillA[2 * t + 1] : 0;
    ps[t] = a0 + a1;
    __syncthreads();
    for (int d = 1; d < 256; d <<= 1) {
      int x = (t >= d) ? ps[t - d] : 0;
      __syncthreads();
      ps[t] += x;
      __syncthreads();
    }
    int pi = bk >> 1;
    int base = (pi ? ps[pi - 1] : 0) + ((bk & 1) ? fillA[bk & ~1] : 0);
    int m = fillA[bk];
    int n0 = bk << BSH;
    if (bk == 0 && t == 0) offs[N] = E;
    const u32* P = pairs + (size_t)bk * BCAP;
    cnt[t] = 0;
    __syncthreads();
    for (int i = t; i < m; i += 256)
      atomicAdd(&cnt[P[i] & 255], 1);
    __syncthreads();
    int v = cnt[t];
    lfill[t] = v;
    __syncthreads();
    for (int d = 1; d < 256; d <<= 1) {
      int a = (t >= d) ? lfill[t - d] : 0;
      __syncthreads();
      lfill[t] += a;
      __syncthreads();
    }
    int excl = lfill[t] - v;
    if (n0 + t < N) offs[n0 + t] = base + excl;
    __syncthreads();
    lfill[t] = excl;
    __syncthreads();
    for (int i = t; i < m; i += 256) {
      u32 p = P[i];
      int pos = atomicAdd(&lfill[p & 255], 1);
      lsrc[pos] = (int)(((p & 15u) << 28) | (p >> 8));   // (dst&15)<<28 | src
    }
    __syncthreads();
    for (int i = t; i < m; i += 256) srcs[base + i] = (u32)lsrc[i];
  }
}

// ---------------- standalone gemm (layer 2): [N,64] @ [64,192], f16 in/out ----------------
__global__ void __launch_bounds__(256) k_gemm2(const f16* __restrict__ Xv,
    const f16* __restrict__ Wfrag, const float* __restrict__ bias,
    f16* __restrict__ O0, f16* __restrict__ O1, f16* __restrict__ O2, int N)
{
  constexpr int KS = 2, K = 64;
  __shared__ f16 wl[12 * KS * 64 * 8];
  const int tid = threadIdx.x;
  {
    const int4* src = (const int4*)Wfrag;
    int4* dst = (int4*)wl;
    const int n16 = 12 * KS * 64;
    for (int i = tid; i < n16; i += 256) dst[i] = src[i];
  }
  __syncthreads();
  int lane = tid & 63, w = tid >> 6;
  int g8 = ((lane >> 4) << 3);
  int r16 = blockIdx.x * 64 + w * 16;
  int rowA = r16 + (lane & 15);
  int rowAc = rowA < N ? rowA : N - 1;
  int colc = lane & 15;
  f32x4 acc[12];
#pragma unroll
  for (int t = 0; t < 12; ++t) {
    float b = bias[t * 16 + colc];
    f32x4 tmp = {b, b, b, b};
    acc[t] = tmp;
  }
#pragma unroll
  for (int s = 0; s < KS; ++s) {
    f16x8 a = *(const f16x8*)(Xv + (size_t)rowAc * K + s * 32 + g8);
#pragma unroll
    for (int t = 0; t < 12; ++t) {
      f16x8 b = *(const f16x8*)&wl[((t * KS + s) * 64 + lane) * 8];
      acc[t] = __builtin_amdgcn_mfma_f32_16x16x32_f16(a, b, acc[t], 0, 0, 0);
    }
  }
  int rowD0 = r16 + ((lane >> 4) << 2);
#pragma unroll
  for (int t = 0; t < 12; ++t) {
    f16* O = (t < 4) ? O0 : (t < 8 ? O1 : O2);
    int c = (t & 3) * 16 + colc;
#pragma unroll
    for (int q = 0; q < 4; ++q) {
      int r = rowD0 + q;
      if (r < N) O[(size_t)r * 64 + c] = (f16)acc[t][q];
    }
  }
}

// ---------------- tile-based segment-matmul GATv2 conv, slim 1-deep pipeline ----------------
// 16 consecutive (16-aligned) nodes per wave = one contiguous CSR edge range.
// Prefetch state per batch: XL (2x f16x8 = 8 VGPR) + dst-nibbles (1) + per-lane dA (1).
// XR loaded at COMPUTE time (tile rows, L1-hot) but issued BEFORE the next-batch prefetch
// (sched_barrier pins order) so the compiler's XR wait is vmcnt(2), leaving the next
// prefetch in flight. Exact tail (no masked-batch inflation).
__global__ void __launch_bounds__(256) k_conv(const int* __restrict__ offs, const u32* __restrict__ srcs,
    const f16* __restrict__ XL, const f16* __restrict__ XR,
    const float* __restrict__ ATT, const float* __restrict__ BC,
    const f16* __restrict__ RES, f16* __restrict__ OH, float* __restrict__ OF,
    int N, int ntiles, int nwaves)
{
  int lane = threadIdx.x & 63, w = threadIdx.x >> 6;
  int g = lane >> 4, c16 = lane & 15;
  int wid = blockIdx.x * 4 + w;

  const float LOG2E = 1.4426950408889634f;
  f16x8 attf0, attf1, Ia, Ib;
#pragma unroll
  for (int j = 0; j < 8; ++j) {
    attf0[j] = (f16)(ATT[g * 8 + j] * LOG2E);
    attf1[j] = (f16)(ATT[32 + g * 8 + j] * LOG2E);
    Ia[j] = (f16)((g * 8 + j == c16) ? 1.f : 0.f);
    Ib[j] = (f16)((g * 8 + j == c16 + 16) ? 1.f : 0.f);
  }
  float bc4[4];
#pragma unroll
  for (int b = 0; b < 4; ++b) bc4[b] = BC[b * 16 + c16];
  const f16 one = (f16)1.f;
  const f16x4 ones = {one, one, one, one};

  for (int tile = wid; tile < ntiles; tile += nwaves) {
    int n0 = tile << 4;
    int nhi = n0 + 16; if (nhi > N) nhi = N;
    int e0 = __builtin_amdgcn_readfirstlane(offs[n0]);
    int e1 = __builtin_amdgcn_readfirstlane(offs[nhi]);
    int cnt = e1 - e0;

    f32x4 agg0 = {0.f, 0.f, 0.f, 0.f}, agg1 = agg0, agg2 = agg0, agg3 = agg0;
    f32x4 den = agg0;

    if (cnt > 0) {
      int nb = (cnt + 15) >> 4;
      int il = e0 + lane;
      u32 my = srcs[il < e1 ? il : e1 - 1];

      // prefetch batch 0: XL + dst-nibbles + per-lane dA
      f16x8 nx0, nx1;
      u32 ndp = 0;
      int ndA = 0;
      {
        u32 vA = __shfl((int)my, c16);
        ndA = (int)(vA >> 28);
        const f16* rp = XL + (size_t)(vA & 0x0FFFFFFFu) * 64;
        nx0 = *(const f16x8*)(rp + g * 8);
        nx1 = *(const f16x8*)(rp + 32 + g * 8);
        u32 w0 = __shfl((int)my, g * 4 + 0);
        u32 w1 = __shfl((int)my, g * 4 + 1);
        u32 w2 = __shfl((int)my, g * 4 + 2);
        u32 w3 = __shfl((int)my, g * 4 + 3);
        ndp = (w0 >> 28) | ((w1 >> 28) << 4) | ((w2 >> 28) << 8) | ((w3 >> 28) << 12);
      }

      for (int fb = 0; fb < nb; ++fb) {
        f16x8 x0 = nx0, x1 = nx1;
        u32 dp = ndp;
        int dA = ndA;
        int ebase = fb << 4;

        // ---- XR loads for CURRENT batch (issued before the next prefetch) ----
        const f16* xp = XR + (size_t)(n0 + dA) * 64;
        f16x8 xr0 = *(const f16x8*)(xp + g * 8);
        f16x8 xr1 = *(const f16x8*)(xp + 32 + g * 8);
        __builtin_amdgcn_sched_barrier(0);

        // ---- prefetch batch fb+1 (XL only) ----
        if (fb + 1 < nb) {
          int nw = (fb + 1) & 3;
          if (nw == 0) {
            int ein = e0 + ((fb + 1) << 4) + lane;
            my = srcs[ein < e1 ? ein : e1 - 1];
          }
          u32 vA = __shfl((int)my, (nw << 4) + c16);
          ndA = (int)(vA >> 28);
          const f16* rp = XL + (size_t)(vA & 0x0FFFFFFFu) * 64;
          nx0 = *(const f16x8*)(rp + g * 8);
          nx1 = *(const f16x8*)(rp + 32 + g * 8);
          u32 w0 = __shfl((int)my, (nw << 4) + g * 4 + 0);
          u32 w1 = __shfl((int)my, (nw << 4) + g * 4 + 1);
          u32 w2 = __shfl((int)my, (nw << 4) + g * 4 + 2);
          u32 w3 = __shfl((int)my, (nw << 4) + g * 4 + 3);
          ndp = (w0 >> 28) | ((w1 >> 28) << 4) | ((w2 >> 28) << 8) | ((w3 >> 28) << 12);
        }

        // ---- compute current batch ----
        f16x8 t0 = x0 + xr0, t1 = x1 + xr1;
        t0 = __builtin_elementwise_max(t0, t0 * (f16)0.2f);
        t1 = __builtin_elementwise_max(t1, t1 * (f16)0.2f);
        f32x4 dot = {0.f, 0.f, 0.f, 0.f};
        dot = __builtin_amdgcn_mfma_f32_16x16x32_f16(t0, attf0, dot, 0, 0, 0);
        dot = __builtin_amdgcn_mfma_f32_16x16x32_f16(t1, attf1, dot, 0, 0, 0);

        f32x4 d0 = {0.f, 0.f, 0.f, 0.f}, d1 = d0, d2 = d0, d3 = d0;
        d0 = __builtin_amdgcn_mfma_f32_16x16x32_f16(x0, Ia, d0, 0, 0, 0);
        d1 = __builtin_amdgcn_mfma_f32_16x16x32_f16(x0, Ib, d1, 0, 0, 0);
        d2 = __builtin_amdgcn_mfma_f32_16x16x32_f16(x1, Ia, d2, 0, 0, 0);
        d3 = __builtin_amdgcn_mfma_f32_16x16x32_f16(x1, Ib, d3, 0, 0, 0);

        int eb = ebase + g * 4;
        float q0 = ((int)((dp >>  0) & 15u) == c16 && eb + 0 < cnt) ? fexp2(dot[0]) : 0.f;
        float q1 = ((int)((dp >>  4) & 15u) == c16 && eb + 1 < cnt) ? fexp2(dot[1]) : 0.f;
        float q2 = ((int)((dp >>  8) & 15u) == c16 && eb + 2 < cnt) ? fexp2(dot[2]) : 0.f;
        float q3 = ((int)((dp >> 12) & 15u) == c16 && eb + 3 < cnt) ? fexp2(dot[3]) : 0.f;
        f16x4 pa  = mk4(pkrtz(q0, q1), pkrtz(q2, q3));
        f16x4 bv0 = mk4(pkrtz(d0[0], d0[1]), pkrtz(d0[2], d0[3]));
        f16x4 bv1 = mk4(pkrtz(d1[0], d1[1]), pkrtz(d1[2], d1[3]));
        f16x4 bv2 = mk4(pkrtz(d2[0], d2[1]), pkrtz(d2[2], d2[3]));
        f16x4 bv3 = mk4(pkrtz(d3[0], d3[1]), pkrtz(d3[2], d3[3]));

        agg0 = __builtin_amdgcn_mfma_f32_16x16x16f16(pa, bv0, agg0, 0, 0, 0);
        agg1 = __builtin_amdgcn_mfma_f32_16x16x16f16(pa, bv1, agg1, 0, 0, 0);
        agg2 = __builtin_amdgcn_mfma_f32_16x16x16f16(pa, bv2, agg2, 0, 0, 0);
        agg3 = __builtin_amdgcn_mfma_f32_16x16x16f16(pa, bv3, agg3, 0, 0, 0);
        den  = __builtin_amdgcn_mfma_f32_16x16x16f16(pa, ones, den, 0, 0, 0);
      }
    }

    // RES tile via vector load + identity MFMAs: r_b[q] = RES[n0+g*4+q][b*16+c16]
    int rowx = n0 + c16; if (rowx >= N) rowx = N - 1;
    const f16* rsp = RES + (size_t)rowx * 64;
    f16x8 rr0 = *(const f16x8*)(rsp + g * 8);
    f16x8 rr1 = *(const f16x8*)(rsp + 32 + g * 8);
    f32x4 r0 = {0.f, 0.f, 0.f, 0.f}, r1 = r0, r2 = r0, r3 = r0;
    r0 = __builtin_amdgcn_mfma_f32_16x16x32_f16(rr0, Ia, r0, 0, 0, 0);
    r1 = __builtin_amdgcn_mfma_f32_16x16x32_f16(rr0, Ib, r1, 0, 0, 0);
    r2 = __builtin_amdgcn_mfma_f32_16x16x32_f16(rr1, Ia, r2, 0, 0, 0);
    r3 = __builtin_amdgcn_mfma_f32_16x16x32_f16(rr1, Ib, r3, 0, 0, 0);

    // lane(g,c16) holds node n0+g*4+q, chan b*16+c16
#pragma unroll
    for (int q = 0; q < 4; ++q) {
      int node = n0 + g * 4 + q;
      if (node >= N) break;
      float dv = den[q];
      float rden = dv > 0.f ? 1.f / dv : 0.f;
#pragma unroll
      for (int b = 0; b < 4; ++b) {
        float av = (b == 0) ? agg0[q] : (b == 1) ? agg1[q] : (b == 2) ? agg2[q] : agg3[q];
        float rv = (b == 0) ? r0[q]   : (b == 1) ? r1[q]   : (b == 2) ? r2[q]   : r3[q];
        float o = av * rden + bc4[b] + rv;
        if (OH) { o = fmaxf(o, 0.f); OH[(size_t)node * 64 + b * 16 + c16] = (f16)o; }
        else    { OF[(size_t)node * 64 + b * 16 + c16] = o; }
      }
    }
  }
}

extern "C" void kernel_launch(void* const* d_in, const int* in_sizes, int n_in,
                              void* d_out, int out_size, void* d_ws, size_t ws_size,
                              hipStream_t stream) {
  const float* x   = (const float*)d_in[0];
  const int*   ei  = (const int*)d_in[1];
  const float* Wl1 = (const float*)d_in[3];
  const float* bl1 = (const float*)d_in[4];
  const float* Wr1 = (const float*)d_in[5];
  const float* br1 = (const float*)d_in[6];
  const float* att1= (const float*)d_in[7];
  const float* bc1 = (const float*)d_in[8];
  const float* W1  = (const float*)d_in[9];
  const float* b1  = (const float*)d_in[10];
  const float* Wl2 = (const float*)d_in[11];
  const float* bl2 = (const float*)d_in[12];
  const float* Wr2 = (const float*)d_in[13];
  const float* br2 = (const float*)d_in[14];
  const float* att2= (const float*)d_in[15];
  const float* bc2 = (const float*)d_in[16];
  const float* W2  = (const float*)d_in[17];
  const float* b2  = (const float*)d_in[18];

  const int N = in_sizes[0] / 128;
  const int E = in_sizes[1] / 2;
  const int NB = (N + 255) >> BSH;

  char* base = (char*)d_ws;
  size_t off = 0;
  auto take = [&](size_t bytes) -> void* {
    void* p = base + off;
    off = (off + bytes + 255) & ~(size_t)255;
    return p;
  };
  int* fillA = (int*)take((size_t)NB * 4);
  int* offs  = (int*)take((size_t)(N + 1) * 4);
  u32* pairs = (u32*)take((size_t)NB * BCAP * 4);
  u32* srcs  = (u32*)take((size_t)E * 4);
  f16* Wf1   = (f16*)take(12 * 4 * 64 * 8 * 2);
  f16* Wf2   = (f16*)take(12 * 2 * 64 * 8 * 2);
  float* bias1 = (float*)take(192 * 4);
  float* bias2 = (float*)take(192 * 4);
  f16* xl  = (f16*)take((size_t)N * 64 * 2);
  f16* xr  = (f16*)take((size_t)N * 64 * 2);
  f16* rs  = (f16*)take((size_t)N * 64 * 2);
  f16* h   = (f16*)take((size_t)N * 64 * 2);

  k_zero<<<(NB + 255) / 256, 256, 0, stream>>>(fillA, NB);

  const int prepN = 12 * 4 * 64 * 8 + 12 * 2 * 64 * 8 + 384;
  const int GP = (prepN + 255) / 256;
  const int GA = (E + 8191) / 8192;
  k_front1<<<GP + GA, 256, 0, stream>>>(Wl1, bl1, Wr1, br1, W1, b1,
                                        Wl2, bl2, Wr2, br2, W2, b2,
                                        Wf1, Wf2, bias1, bias2,
                                        ei, fillA, pairs, E, NB, GP);

  const int GG = (N + 63) / 64;
  k_front2<<<GG + NB, 256, 0, stream>>>(x, Wf1, bias1, xl, xr, rs, N, GG,
                                        pairs, fillA, srcs, offs, NB, E);

  const int ntiles = (N + 15) / 16;
  const int CB = 1563, CW = CB * 4;   // ~1 tile per wave
  k_conv<<<CB, 256, 0, stream>>>(offs, srcs, xl, xr, att1, bc1, rs, h, nullptr, N, ntiles, CW);
  k_gemm2<<<GG, 256, 0, stream>>>(h, Wf2, bias2, xl, xr, rs, N);
  k_conv<<<CB, 256, 0, stream>>>(offs, srcs, xl, xr, att2, bc2, rs, nullptr, (float*)d_out, N, ntiles, CW);
}

// Round 16
// 178.476 us; speedup vs baseline: 1.1584x; 1.0885x over previous
//
#include <hip/hip_runtime.h>

typedef unsigned short u16;
typedef unsigned int u32;
typedef _Float16 f16;
typedef __attribute__((ext_vector_type(4))) _Float16 f16x4;
typedef __attribute__((ext_vector_type(8))) _Float16 f16x8;
typedef __attribute__((ext_vector_type(4))) float f32x4;
typedef __fp16 hh2 __attribute__((ext_vector_type(2)));

#define BCAP 8192          // per-bucket pair capacity (mean 4096, sd 64)
#define BSH  8             // 256 nodes per bucket

__device__ __forceinline__ u32 pkrtz(float a, float b) {
  hh2 r = __builtin_amdgcn_cvt_pkrtz(a, b);
  union { hh2 h; u32 u; } c; c.h = r; return c.u;
}
__device__ __forceinline__ f16x4 mk4(u32 lo, u32 hi) {
  union { u32 u[2]; f16x4 h; } c; c.u[0] = lo; c.u[1] = hi; return c.h;
}
__device__ __forceinline__ f16x8 mk8(u32 a, u32 b, u32 c_, u32 d) {
  union { u32 u[4]; f16x8 h; } c; c.u[0] = a; c.u[1] = b; c.u[2] = c_; c.u[3] = d; return c.h;
}
__device__ __forceinline__ float fexp2(float x) {
  float r; asm("v_exp_f32 %0, %1" : "=v"(r) : "v"(x)); return r;
}

// ---------------- tiny zero kernel ----------------
__global__ void __launch_bounds__(256) k_zero(int* __restrict__ p, int n) {
  int i = threadIdx.x + blockIdx.x * 256;
  if (i < n) p[i] = 0;
}

// ---------------- front1: weight-prep blocks + bucketA blocks (independent) ----------------
__global__ void __launch_bounds__(256) k_front1(
    const float* __restrict__ Wl1, const float* __restrict__ bl1,
    const float* __restrict__ Wr1, const float* __restrict__ br1,
    const float* __restrict__ W1,  const float* __restrict__ b1,
    const float* __restrict__ Wl2, const float* __restrict__ bl2,
    const float* __restrict__ Wr2, const float* __restrict__ br2,
    const float* __restrict__ W2,  const float* __restrict__ b2,
    f16* __restrict__ Wf1, f16* __restrict__ Wf2,
    float* __restrict__ bias1, float* __restrict__ bias2,
    const int* __restrict__ ei, int* __restrict__ fillA, u32* __restrict__ pairs,
    int E, int NB, int GP)
{
  __shared__ int sm[1024];
  int b = blockIdx.x;
  int t = threadIdx.x;
  if (b < GP) {
    int g = b * 256 + t;
    const int NP1 = 12 * 4 * 64 * 8;   // 24576
    const int NP2 = 12 * 2 * 64 * 8;   // 12288
    if (g < NP1) {
      int j = g & 7, l = (g >> 3) & 63, s = (g >> 9) & 3, tt = g >> 11;
      int k = s * 32 + ((l >> 4) << 3) + j;
      int c = tt * 16 + (l & 15);
      const float* W = (c < 64) ? Wl1 : (c < 128 ? Wr1 : W1);
      Wf1[g] = (f16)W[k * 64 + (c & 63)];
    } else if (g < NP1 + NP2) {
      int g2 = g - NP1;
      int j = g2 & 7, l = (g2 >> 3) & 63, s = (g2 >> 9) & 1, tt = g2 >> 10;
      int k = s * 32 + ((l >> 4) << 3) + j;
      int c = tt * 16 + (l & 15);
      const float* W = (c < 64) ? Wl2 : (c < 128 ? Wr2 : W2);
      Wf2[g2] = (f16)W[k * 64 + (c & 63)];
    } else if (g < NP1 + NP2 + 192) {
      int c = g - NP1 - NP2;
      bias1[c] = (c < 64) ? bl1[c] : (c < 128 ? br1[c - 64] : b1[c - 128]);
    } else if (g < NP1 + NP2 + 384) {
      int c = g - NP1 - NP2 - 192;
      bias2[c] = (c < 64) ? bl2[c] : (c < 128 ? br2[c - 64] : b2[c - 128]);
    }
  } else {
    int* lhist = sm;
    int* lbase = sm + 512;
    int c0 = (b - GP) * 8192;
    int n = E - c0; if (n > 8192) n = 8192;
    for (int i = t; i < NB; i += 256) lhist[i] = 0;
    __syncthreads();
    for (int i = t; i < n; i += 256)
      atomicAdd(&lhist[ei[E + c0 + i] >> BSH], 1);
    __syncthreads();
    for (int i = t; i < NB; i += 256) {
      int h = lhist[i];
      lbase[i] = h ? atomicAdd(&fillA[i], h) : 0;
      lhist[i] = 0;
    }
    __syncthreads();
    for (int i = t; i < n; i += 256) {
      int s = ei[c0 + i], d = ei[E + c0 + i];
      int bk = d >> BSH;
      int pos = lbase[bk] + atomicAdd(&lhist[bk], 1);
      if (pos < BCAP) pairs[(size_t)bk * BCAP + pos] = ((u32)s << 8) | (u32)(d & 255);
    }
  }
}

// ---------------- front2: gemm1 blocks + bucketB blocks (independent) ----------------
// bucketB packs srcs as (dst&15)<<28 | src  (src < 2^24) for the tile-based conv.
__global__ void __launch_bounds__(256) k_front2(
    const float* __restrict__ X, const f16* __restrict__ Wfrag, const float* __restrict__ bias,
    f16* __restrict__ O0, f16* __restrict__ O1, f16* __restrict__ O2, int N, int GG,
    const u32* __restrict__ pairs, const int* __restrict__ fillA,
    u32* __restrict__ srcs, int* __restrict__ offs, int NB, int E)
{
  __shared__ __align__(16) char smraw[49152];
  int b = blockIdx.x;
  int t = threadIdx.x;
  if (b < GG) {
    constexpr int KS = 4, K = 128;
    f16* wl = (f16*)smraw;
    {
      const int4* src = (const int4*)Wfrag;
      int4* dst = (int4*)wl;
      const int n16 = 12 * KS * 64;
      for (int i = t; i < n16; i += 256) dst[i] = src[i];
    }
    __syncthreads();
    int lane = t & 63, w = t >> 6;
    int g8 = ((lane >> 4) << 3);
    int r16 = b * 64 + w * 16;
    int rowA = r16 + (lane & 15);
    int rowAc = rowA < N ? rowA : N - 1;
    int colc = lane & 15;
    f32x4 acc[12];
#pragma unroll
    for (int tt = 0; tt < 12; ++tt) {
      float bb_ = bias[tt * 16 + colc];
      f32x4 tmp = {bb_, bb_, bb_, bb_};
      acc[tt] = tmp;
    }
#pragma unroll
    for (int s = 0; s < KS; ++s) {
      const float* xp = X + (size_t)rowAc * K + s * 32 + g8;
      float4 x0 = *(const float4*)xp;
      float4 x1 = *(const float4*)(xp + 4);
      f16x8 a = mk8(pkrtz(x0.x, x0.y), pkrtz(x0.z, x0.w),
                    pkrtz(x1.x, x1.y), pkrtz(x1.z, x1.w));
#pragma unroll
      for (int tt = 0; tt < 12; ++tt) {
        f16x8 bb_ = *(const f16x8*)&wl[((tt * KS + s) * 64 + lane) * 8];
        acc[tt] = __builtin_amdgcn_mfma_f32_16x16x32_f16(a, bb_, acc[tt], 0, 0, 0);
      }
    }
    int rowD0 = r16 + ((lane >> 4) << 2);
#pragma unroll
    for (int tt = 0; tt < 12; ++tt) {
      f16* O = (tt < 4) ? O0 : (tt < 8 ? O1 : O2);
      int c = (tt & 3) * 16 + colc;
#pragma unroll
      for (int q = 0; q < 4; ++q) {
        int r = rowD0 + q;
        if (r < N) O[(size_t)r * 64 + c] = (f16)acc[tt][q];
      }
    }
  } else {
    int* cnt   = (int*)smraw;
    int* lfill = cnt + 256;
    int* ps    = lfill + 256;
    int* lsrc  = ps + 256;
    int bk = b - GG;
    int a0 = (2 * t < NB) ? fillA[2 * t] : 0;
    int a1 = (2 * t + 1 < NB) ? fillA[2 * t + 1] : 0;
    ps[t] = a0 + a1;
    __syncthreads();
    for (int d = 1; d < 256; d <<= 1) {
      int x = (t >= d) ? ps[t - d] : 0;
      __syncthreads();
      ps[t] += x;
      __syncthreads();
    }
    int pi = bk >> 1;
    int base = (pi ? ps[pi - 1] : 0) + ((bk & 1) ? fillA[bk & ~1] : 0);
    int m = fillA[bk];
    int n0 = bk << BSH;
    if (bk == 0 && t == 0) offs[N] = E;
    const u32* P = pairs + (size_t)bk * BCAP;
    cnt[t] = 0;
    __syncthreads();
    for (int i = t; i < m; i += 256)
      atomicAdd(&cnt[P[i] & 255], 1);
    __syncthreads();
    int v = cnt[t];
    lfill[t] = v;
    __syncthreads();
    for (int d = 1; d < 256; d <<= 1) {
      int a = (t >= d) ? lfill[t - d] : 0;
      __syncthreads();
      lfill[t] += a;
      __syncthreads();
    }
    int excl = lfill[t] - v;
    if (n0 + t < N) offs[n0 + t] = base + excl;
    __syncthreads();
    lfill[t] = excl;
    __syncthreads();
    for (int i = t; i < m; i += 256) {
      u32 p = P[i];
      int pos = atomicAdd(&lfill[p & 255], 1);
      lsrc[pos] = (int)(((p & 15u) << 28) | (p >> 8));   // (dst&15)<<28 | src
    }
    __syncthreads();
    for (int i = t; i < m; i += 256) srcs[base + i] = (u32)lsrc[i];
  }
}

// ---------------- standalone gemm (layer 2): [N,64] @ [64,192], f16 in/out ----------------
__global__ void __launch_bounds__(256) k_gemm2(const f16* __restrict__ Xv,
    const f16* __restrict__ Wfrag, const float* __restrict__ bias,
    f16* __restrict__ O0, f16* __restrict__ O1, f16* __restrict__ O2, int N)
{
  constexpr int KS = 2, K = 64;
  __shared__ f16 wl[12 * KS * 64 * 8];
  const int tid = threadIdx.x;
  {
    const int4* src = (const int4*)Wfrag;
    int4* dst = (int4*)wl;
    const int n16 = 12 * KS * 64;
    for (int i = tid; i < n16; i += 256) dst[i] = src[i];
  }
  __syncthreads();
  int lane = tid & 63, w = tid >> 6;
  int g8 = ((lane >> 4) << 3);
  int r16 = blockIdx.x * 64 + w * 16;
  int rowA = r16 + (lane & 15);
  int rowAc = rowA < N ? rowA : N - 1;
  int colc = lane & 15;
  f32x4 acc[12];
#pragma unroll
  for (int t = 0; t < 12; ++t) {
    float b = bias[t * 16 + colc];
    f32x4 tmp = {b, b, b, b};
    acc[t] = tmp;
  }
#pragma unroll
  for (int s = 0; s < KS; ++s) {
    f16x8 a = *(const f16x8*)(Xv + (size_t)rowAc * K + s * 32 + g8);
#pragma unroll
    for (int t = 0; t < 12; ++t) {
      f16x8 b = *(const f16x8*)&wl[((t * KS + s) * 64 + lane) * 8];
      acc[t] = __builtin_amdgcn_mfma_f32_16x16x32_f16(a, b, acc[t], 0, 0, 0);
    }
  }
  int rowD0 = r16 + ((lane >> 4) << 2);
#pragma unroll
  for (int t = 0; t < 12; ++t) {
    f16* O = (t < 4) ? O0 : (t < 8 ? O1 : O2);
    int c = (t & 3) * 16 + colc;
#pragma unroll
    for (int q = 0; q < 4; ++q) {
      int r = rowD0 + q;
      if (r < N) O[(size_t)r * 64 + c] = (f16)acc[t][q];
    }
  }
}

// ---------------- tile-based segment-matmul GATv2 conv, 1-deep pipeline (R13 optimum) --------
// 16 consecutive (16-aligned) nodes per wave = one contiguous CSR edge range.
// Prefetch batch fb+1's shfls + XL + XR gathers before computing batch fb
// (double-buffered in registers). Exact tail, no masked-batch inflation.
__global__ void __launch_bounds__(256) k_conv(const int* __restrict__ offs, const u32* __restrict__ srcs,
    const f16* __restrict__ XL, const f16* __restrict__ XR,
    const float* __restrict__ ATT, const float* __restrict__ BC,
    const f16* __restrict__ RES, f16* __restrict__ OH, float* __restrict__ OF,
    int N, int ntiles, int nwaves)
{
  int lane = threadIdx.x & 63, w = threadIdx.x >> 6;
  int g = lane >> 4, c16 = lane & 15;
  int wid = blockIdx.x * 4 + w;

  const float LOG2E = 1.4426950408889634f;
  f16x8 attf0, attf1, Ia, Ib;
#pragma unroll
  for (int j = 0; j < 8; ++j) {
    attf0[j] = (f16)(ATT[g * 8 + j] * LOG2E);
    attf1[j] = (f16)(ATT[32 + g * 8 + j] * LOG2E);
    Ia[j] = (f16)((g * 8 + j == c16) ? 1.f : 0.f);
    Ib[j] = (f16)((g * 8 + j == c16 + 16) ? 1.f : 0.f);
  }
  float bc4[4];
#pragma unroll
  for (int b = 0; b < 4; ++b) bc4[b] = BC[b * 16 + c16];
  const f16 one = (f16)1.f;
  const f16x4 ones = {one, one, one, one};

  for (int tile = wid; tile < ntiles; tile += nwaves) {
    int n0 = tile << 4;
    int nhi = n0 + 16; if (nhi > N) nhi = N;
    int e0 = __builtin_amdgcn_readfirstlane(offs[n0]);
    int e1 = __builtin_amdgcn_readfirstlane(offs[nhi]);
    int cnt = e1 - e0;

    f32x4 agg0 = {0.f, 0.f, 0.f, 0.f}, agg1 = agg0, agg2 = agg0, agg3 = agg0;
    f32x4 den = agg0;

    if (cnt > 0) {
      int nb = (cnt + 15) >> 4;
      int il = e0 + lane;
      u32 my = srcs[il < e1 ? il : e1 - 1];

      // prefetch batch 0
      f16x8 nx0, nx1, nxr0, nxr1;
      u32 nv0, nv1, nv2, nv3;
      {
        u32 vA = __shfl((int)my, c16);
        int sA = (int)(vA & 0x0FFFFFFFu);
        int dA = (int)(vA >> 28);
        const f16* rp = XL + (size_t)sA * 64;
        nx0 = *(const f16x8*)(rp + g * 8);
        nx1 = *(const f16x8*)(rp + 32 + g * 8);
        const f16* xp = XR + (size_t)(n0 + dA) * 64;
        nxr0 = *(const f16x8*)(xp + g * 8);
        nxr1 = *(const f16x8*)(xp + 32 + g * 8);
        nv0 = __shfl((int)my, g * 4 + 0);
        nv1 = __shfl((int)my, g * 4 + 1);
        nv2 = __shfl((int)my, g * 4 + 2);
        nv3 = __shfl((int)my, g * 4 + 3);
      }

      for (int fb = 0; fb < nb; ++fb) {
        f16x8 x0 = nx0, x1 = nx1, xr0 = nxr0, xr1 = nxr1;
        u32 v0 = nv0, v1 = nv1, v2 = nv2, v3 = nv3;
        int ebase = fb << 4;

        // ---- prefetch batch fb+1 (wave-uniform guards) ----
        if (fb + 1 < nb) {
          int nw = (fb + 1) & 3;
          if (nw == 0) {
            int ein = e0 + ((fb + 1) << 4) + lane;
            my = srcs[ein < e1 ? ein : e1 - 1];
          }
          u32 vA = __shfl((int)my, (nw << 4) + c16);
          int sA = (int)(vA & 0x0FFFFFFFu);
          int dA = (int)(vA >> 28);
          const f16* rp = XL + (size_t)sA * 64;
          nx0 = *(const f16x8*)(rp + g * 8);
          nx1 = *(const f16x8*)(rp + 32 + g * 8);
          const f16* xp = XR + (size_t)(n0 + dA) * 64;
          nxr0 = *(const f16x8*)(xp + g * 8);
          nxr1 = *(const f16x8*)(xp + 32 + g * 8);
          nv0 = __shfl((int)my, (nw << 4) + g * 4 + 0);
          nv1 = __shfl((int)my, (nw << 4) + g * 4 + 1);
          nv2 = __shfl((int)my, (nw << 4) + g * 4 + 2);
          nv3 = __shfl((int)my, (nw << 4) + g * 4 + 3);
        }

        // ---- compute current batch ----
        f16x8 t0 = x0 + xr0, t1 = x1 + xr1;
        t0 = __builtin_elementwise_max(t0, t0 * (f16)0.2f);
        t1 = __builtin_elementwise_max(t1, t1 * (f16)0.2f);
        f32x4 dot = {0.f, 0.f, 0.f, 0.f};
        dot = __builtin_amdgcn_mfma_f32_16x16x32_f16(t0, attf0, dot, 0, 0, 0);
        dot = __builtin_amdgcn_mfma_f32_16x16x32_f16(t1, attf1, dot, 0, 0, 0);

        f32x4 d0 = {0.f, 0.f, 0.f, 0.f}, d1 = d0, d2 = d0, d3 = d0;
        d0 = __builtin_amdgcn_mfma_f32_16x16x32_f16(x0, Ia, d0, 0, 0, 0);
        d1 = __builtin_amdgcn_mfma_f32_16x16x32_f16(x0, Ib, d1, 0, 0, 0);
        d2 = __builtin_amdgcn_mfma_f32_16x16x32_f16(x1, Ia, d2, 0, 0, 0);
        d3 = __builtin_amdgcn_mfma_f32_16x16x32_f16(x1, Ib, d3, 0, 0, 0);

        float q0, q1, q2, q3;
        {
          int eb = ebase + g * 4;
          q0 = ((int)(v0 >> 28) == c16 && eb + 0 < cnt) ? fexp2(dot[0]) : 0.f;
          q1 = ((int)(v1 >> 28) == c16 && eb + 1 < cnt) ? fexp2(dot[1]) : 0.f;
          q2 = ((int)(v2 >> 28) == c16 && eb + 2 < cnt) ? fexp2(dot[2]) : 0.f;
          q3 = ((int)(v3 >> 28) == c16 && eb + 3 < cnt) ? fexp2(dot[3]) : 0.f;
        }
        f16x4 pa  = mk4(pkrtz(q0, q1), pkrtz(q2, q3));
        f16x4 bv0 = mk4(pkrtz(d0[0], d0[1]), pkrtz(d0[2], d0[3]));
        f16x4 bv1 = mk4(pkrtz(d1[0], d1[1]), pkrtz(d1[2], d1[3]));
        f16x4 bv2 = mk4(pkrtz(d2[0], d2[1]), pkrtz(d2[2], d2[3]));
        f16x4 bv3 = mk4(pkrtz(d3[0], d3[1]), pkrtz(d3[2], d3[3]));

        agg0 = __builtin_amdgcn_mfma_f32_16x16x16f16(pa, bv0, agg0, 0, 0, 0);
        agg1 = __builtin_amdgcn_mfma_f32_16x16x16f16(pa, bv1, agg1, 0, 0, 0);
        agg2 = __builtin_amdgcn_mfma_f32_16x16x16f16(pa, bv2, agg2, 0, 0, 0);
        agg3 = __builtin_amdgcn_mfma_f32_16x16x16f16(pa, bv3, agg3, 0, 0, 0);
        den  = __builtin_amdgcn_mfma_f32_16x16x16f16(pa, ones, den, 0, 0, 0);
      }
    }

    // RES tile via vector load + identity MFMAs: r_b[q] = RES[n0+g*4+q][b*16+c16]
    int rowx = n0 + c16; if (rowx >= N) rowx = N - 1;
    const f16* rsp = RES + (size_t)rowx * 64;
    f16x8 rr0 = *(const f16x8*)(rsp + g * 8);
    f16x8 rr1 = *(const f16x8*)(rsp + 32 + g * 8);
    f32x4 r0 = {0.f, 0.f, 0.f, 0.f}, r1 = r0, r2 = r0, r3 = r0;
    r0 = __builtin_amdgcn_mfma_f32_16x16x32_f16(rr0, Ia, r0, 0, 0, 0);
    r1 = __builtin_amdgcn_mfma_f32_16x16x32_f16(rr0, Ib, r1, 0, 0, 0);
    r2 = __builtin_amdgcn_mfma_f32_16x16x32_f16(rr1, Ia, r2, 0, 0, 0);
    r3 = __builtin_amdgcn_mfma_f32_16x16x32_f16(rr1, Ib, r3, 0, 0, 0);

    // lane(g,c16) holds node n0+g*4+q, chan b*16+c16
#pragma unroll
    for (int q = 0; q < 4; ++q) {
      int node = n0 + g * 4 + q;
      if (node >= N) break;
      float dv = den[q];
      float rden = dv > 0.f ? 1.f / dv : 0.f;
#pragma unroll
      for (int b = 0; b < 4; ++b) {
        float av = (b == 0) ? agg0[q] : (b == 1) ? agg1[q] : (b == 2) ? agg2[q] : agg3[q];
        float rv = (b == 0) ? r0[q]   : (b == 1) ? r1[q]   : (b == 2) ? r2[q]   : r3[q];
        float o = av * rden + bc4[b] + rv;
        if (OH) { o = fmaxf(o, 0.f); OH[(size_t)node * 64 + b * 16 + c16] = (f16)o; }
        else    { OF[(size_t)node * 64 + b * 16 + c16] = o; }
      }
    }
  }
}

extern "C" void kernel_launch(void* const* d_in, const int* in_sizes, int n_in,
                              void* d_out, int out_size, void* d_ws, size_t ws_size,
                              hipStream_t stream) {
  const float* x   = (const float*)d_in[0];
  const int*   ei  = (const int*)d_in[1];
  const float* Wl1 = (const float*)d_in[3];
  const float* bl1 = (const float*)d_in[4];
  const float* Wr1 = (const float*)d_in[5];
  const float* br1 = (const float*)d_in[6];
  const float* att1= (const float*)d_in[7];
  const float* bc1 = (const float*)d_in[8];
  const float* W1  = (const float*)d_in[9];
  const float* b1  = (const float*)d_in[10];
  const float* Wl2 = (const float*)d_in[11];
  const float* bl2 = (const float*)d_in[12];
  const float* Wr2 = (const float*)d_in[13];
  const float* br2 = (const float*)d_in[14];
  const float* att2= (const float*)d_in[15];
  const float* bc2 = (const float*)d_in[16];
  const float* W2  = (const float*)d_in[17];
  const float* b2  = (const float*)d_in[18];

  const int N = in_sizes[0] / 128;
  const int E = in_sizes[1] / 2;
  const int NB = (N + 255) >> BSH;

  char* base = (char*)d_ws;
  size_t off = 0;
  auto take = [&](size_t bytes) -> void* {
    void* p = base + off;
    off = (off + bytes + 255) & ~(size_t)255;
    return p;
  };
  int* fillA = (int*)take((size_t)NB * 4);
  int* offs  = (int*)take((size_t)(N + 1) * 4);
  u32* pairs = (u32*)take((size_t)NB * BCAP * 4);
  u32* srcs  = (u32*)take((size_t)E * 4);
  f16* Wf1   = (f16*)take(12 * 4 * 64 * 8 * 2);
  f16* Wf2   = (f16*)take(12 * 2 * 64 * 8 * 2);
  float* bias1 = (float*)take(192 * 4);
  float* bias2 = (float*)take(192 * 4);
  f16* xl  = (f16*)take((size_t)N * 64 * 2);
  f16* xr  = (f16*)take((size_t)N * 64 * 2);
  f16* rs  = (f16*)take((size_t)N * 64 * 2);
  f16* h   = (f16*)take((size_t)N * 64 * 2);

  k_zero<<<(NB + 255) / 256, 256, 0, stream>>>(fillA, NB);

  const int prepN = 12 * 4 * 64 * 8 + 12 * 2 * 64 * 8 + 384;
  const int GP = (prepN + 255) / 256;
  const int GA = (E + 8191) / 8192;
  k_front1<<<GP + GA, 256, 0, stream>>>(Wl1, bl1, Wr1, br1, W1, b1,
                                        Wl2, bl2, Wr2, br2, W2, b2,
                                        Wf1, Wf2, bias1, bias2,
                                        ei, fillA, pairs, E, NB, GP);

  const int GG = (N + 63) / 64;
  k_front2<<<GG + NB, 256, 0, stream>>>(x, Wf1, bias1, xl, xr, rs, N, GG,
                                        pairs, fillA, srcs, offs, NB, E);

  const int ntiles = (N + 15) / 16;
  const int CB = 1563, CW = CB * 4;   // ~1 tile per wave
  k_conv<<<CB, 256, 0, stream>>>(offs, srcs, xl, xr, att1, bc1, rs, h, nullptr, N, ntiles, CW);
  k_gemm2<<<GG, 256, 0, stream>>>(h, Wf2, bias2, xl, xr, rs, N);
  k_conv<<<CB, 256, 0, stream>>>(offs, srcs, xl, xr, att2, bc2, rs, nullptr, (float*)d_out, N, ntiles, CW);
}